// Round 1
// baseline (1363.432 us; speedup 1.0000x reference)
//
#include <hip/hip_runtime.h>

constexpr int N_NODES = 50000;
constexpr int E_EDGES = 1600000;
constexpr int NH      = N_NODES * 32;   // 1,600,000
constexpr float BN_EPS = 1e-5f;
constexpr int NPAD    = 50176;          // 196*256, >= N_NODES+1

// CSR mega-kernel geometry: 196 blocks < 256 CUs => all blocks guaranteed
// co-resident => spin grid-barriers are deadlock-free (G16 discipline:
// device-scope acquire/release, no dispatch-order assumptions).
constexpr int CSR_BLOCKS  = 196;
constexpr int CSR_THREADS = 1024;
constexpr int CSR_TOTAL   = CSR_BLOCKS * CSR_THREADS;   // 200704

// fused gather+fc1 geometry: each block owns 40 nodes = 1280 rres columns
constexpr int GBLK   = 1250;
constexpr int GNODES = 40;
constexpr int GCHUNK = GNODES * 32;     // 1280 floats; NH/GCHUNK = 1250

// ---------------------------------------------------------------- zero scratch
// zeroes ctrl[16] + counts[NPAD]  (contiguous at ws start, 12548 float4s)
__global__ void zero_kernel(float4* __restrict__ p, int n4) {
    int i = blockIdx.x * blockDim.x + threadIdx.x;
    if (i < n4) p[i] = make_float4(0.f, 0.f, 0.f, 0.f);
}

// ---------------------------------------------------------------- helpers
__device__ inline int block_excl_scan(int v, int* s) {
    int t = threadIdx.x;
    s[t] = v;
    __syncthreads();
    for (int d = 1; d < CSR_THREADS; d <<= 1) {
        int x = (t >= d) ? s[t - d] : 0;
        __syncthreads();
        s[t] += x;
        __syncthreads();
    }
    return s[t] - v;   // exclusive
}

__device__ inline void grid_barrier(int* ctr, int target) {
    __syncthreads();
    if (threadIdx.x == 0) {
        __threadfence();   // release this block's prior writes (device scope)
        __hip_atomic_fetch_add(ctr, 1, __ATOMIC_ACQ_REL, __HIP_MEMORY_SCOPE_AGENT);
        while (__hip_atomic_load(ctr, __ATOMIC_ACQUIRE, __HIP_MEMORY_SCOPE_AGENT) < target) {
            __builtin_amdgcn_s_sleep(1);
        }
    }
    __syncthreads();
    __threadfence();       // acquire side for all threads of the block
}

// ---------------------------------------------------------------- CSR build:
// hist -> barrier -> two-level scan -> barrier -> place, one launch.
__global__ __launch_bounds__(CSR_THREADS)
void csr_kernel(const int* __restrict__ ei, const float* __restrict__ ew,
                int* __restrict__ ctrl, int* __restrict__ counts,
                int* __restrict__ off, int* __restrict__ cursor,
                int* __restrict__ bsum, int2* __restrict__ ep) {
    __shared__ int s[CSR_THREADS];
    int tid = blockIdx.x * CSR_THREADS + threadIdx.x;

    // phase 1: histogram of destinations (fire-and-forget atomics)
    for (int e = tid; e < E_EDGES; e += CSR_TOTAL)
        atomicAdd(&counts[ei[E_EDGES + e]], 1);
    grid_barrier(&ctrl[0], CSR_BLOCKS);

    // phase 2: exclusive scan (block-local + cross-block via bsum)
    int v = (tid < N_NODES) ? counts[tid] : 0;
    int excl = block_excl_scan(v, s);
    if (threadIdx.x == CSR_THREADS - 1) bsum[blockIdx.x] = excl + v;  // block total
    grid_barrier(&ctrl[1], CSR_BLOCKS);

    int bv = (threadIdx.x < CSR_BLOCKS) ? bsum[threadIdx.x] : 0;
    int bexcl = block_excl_scan(bv, s);
    __syncthreads();
    s[threadIdx.x] = bexcl;
    __syncthreads();
    int blockoff = s[blockIdx.x];

    if (tid < N_NODES) {
        int o = blockoff + excl;
        off[tid] = o;
        cursor[tid] = o;
    }
    if (tid == N_NODES - 1) off[N_NODES] = blockoff + excl + v;   // == E
    grid_barrier(&ctrl[2], CSR_BLOCKS);

    // phase 3: place edges (tagged src | self-loop bit, weight bits)
    for (int e = tid; e < E_EDGES; e += CSR_TOTAL) {
        int src = ei[e];
        int dst = ei[E_EDGES + e];
        int pos = atomicAdd(&cursor[dst], 1);
        ep[pos] = make_int2(src | ((src == dst) ? 0x80000000 : 0),
                            __float_as_int(ew[e]));
    }
}

// ---------------------------------------------------------------- fused
// gather (BN + weighted neighbor sum + 32x32 W-contraction + relu -> LDS)
// + fc1 chunk (64 rows x 1280 cols) + last-block reduce/fc2 head.
// rres never round-trips HBM; one launch replaces three.
__global__ void gfc_kernel(const float* __restrict__ x,
                           const float* __restrict__ gamma,
                           const float* __restrict__ beta,
                           const float* __restrict__ mean,
                           const float* __restrict__ var,
                           const int*   __restrict__ off,
                           const int2*  __restrict__ ep,
                           const float* __restrict__ W,
                           const float* __restrict__ fc1_w,
                           const float* __restrict__ fc1_b,
                           const float* __restrict__ fc2_w,
                           const float* __restrict__ fc2_b,
                           float* __restrict__ partial,
                           int*   __restrict__ ctrl,
                           float* __restrict__ out) {
    __shared__ float  s_w0[1024], s_wsum[1024];
    __shared__ float4 s_r4[GCHUNK / 4];
    __shared__ int    s_last;
    float* s_r = (float*)s_r4;

    int tid = threadIdx.x;
    for (int idx = tid; idx < 1024; idx += 256) {
        s_w0[idx]   = W[idx];
        s_wsum[idx] = W[1024 + idx] + W[2048 + idx];
    }
    __syncthreads();

    // ---- phase A: gather 40 nodes into s_r
    int c     = tid & 31;
    int gbase = tid & 32;                 // group base lane within the wave
    float sc = gamma[c] * rsqrtf(var[c] + BN_EPS);
    float sh = beta[c] - mean[c] * sc;
    int n0 = blockIdx.x * GNODES;

    for (int r = tid >> 5; r < GNODES; r += 8) {
        int n  = n0 + r;
        int e0 = off[n];
        int nb = off[n + 1] - e0;
        const int2* e2 = ep + e0;
        float acc = 0.f, acc0 = 0.f;

        int base = 0;
        for (; base + 32 <= nb; base += 32) {       // full batches
            int2 p = e2[base + c];
            int sw = p.x; float wv = __int_as_float(p.y);
#pragma unroll 8
            for (int j = 0; j < 32; j++) {
                int   swj = __shfl(sw, gbase + j);
                float wj  = __shfl(wv, gbase + j);
                float vv  = fmaf(x[(swj & 0x7fffffff) * 32 + c], sc, sh);
                acc = fmaf(wj, vv, acc);
                if (swj < 0) acc0 += vv;
            }
        }
        int rem = nb - base;
        if (rem > 0) {                               // tail batch
            int sw = 0; float wv = 0.f;
            if (c < rem) { int2 p = e2[base + c]; sw = p.x; wv = __int_as_float(p.y); }
            for (int j = 0; j < rem; j++) {
                int   swj = __shfl(sw, gbase + j);
                float wj  = __shfl(wv, gbase + j);
                float vv  = fmaf(x[(swj & 0x7fffffff) * 32 + c], sc, sh);
                acc = fmaf(wj, vv, acc);
                if (swj < 0) acc0 += vv;
            }
        }
        float rr = 0.f;
#pragma unroll
        for (int cc = 0; cc < 32; cc++) {
            float a  = __shfl(acc,  gbase + cc);
            float a0 = __shfl(acc0, gbase + cc);
            rr = fmaf(a,  s_wsum[cc * 32 + c], rr);
            rr = fmaf(a0, s_w0  [cc * 32 + c], rr);
        }
        s_r[r * 32 + c] = fmaxf(rr, 0.f);
    }
    __syncthreads();

    // ---- phase B: fc1 chunk, 16 rows per wave, k-loop 5 float4s/lane
    int wave = tid >> 6, lane = tid & 63;
    size_t ib = (size_t)blockIdx.x * GCHUNK;
    float* pout = partial + blockIdx.x * 64;
    for (int jj = 0; jj < 16; jj += 2) {
        int j0 = wave * 16 + jj;
        const float4* wa = (const float4*)(fc1_w + (size_t)j0       * NH + ib);
        const float4* wb = (const float4*)(fc1_w + (size_t)(j0 + 1) * NH + ib);
        float a0 = 0.f, a1 = 0.f;
#pragma unroll
        for (int k = 0; k < GCHUNK / 256; k++) {     // 5
            float4 rv = s_r4[lane + k * 64];
            float4 x0 = wa[lane + k * 64];
            float4 x1 = wb[lane + k * 64];
            a0 = fmaf(rv.x, x0.x, a0); a0 = fmaf(rv.y, x0.y, a0);
            a0 = fmaf(rv.z, x0.z, a0); a0 = fmaf(rv.w, x0.w, a0);
            a1 = fmaf(rv.x, x1.x, a1); a1 = fmaf(rv.y, x1.y, a1);
            a1 = fmaf(rv.z, x1.z, a1); a1 = fmaf(rv.w, x1.w, a1);
        }
#pragma unroll
        for (int o = 32; o > 0; o >>= 1) {
            a0 += __shfl_down(a0, o);
            a1 += __shfl_down(a1, o);
        }
        if (lane == 0) {
            pout[j0]     = a0;
            pout[j0 + 1] = a1;
        }
    }

    // ---- phase C: last-arriving block reduces partial[1250][64] + fc2 head
    __threadfence();                                 // release partial stores
    __syncthreads();
    if (tid == 0) {
        int prev = __hip_atomic_fetch_add(&ctrl[3], 1, __ATOMIC_ACQ_REL,
                                          __HIP_MEMORY_SCOPE_AGENT);
        s_last = (prev == GBLK - 1);
    }
    __syncthreads();
    if (s_last) {
        __threadfence();                             // acquire for all lanes
        float* red = s_w0;                           // reuse (synced above)
        int j = tid & 63, sl = tid >> 6;             // 4 slices over 1250 blocks
        float a = 0.f;
#pragma unroll 4
        for (int b = sl; b < GBLK; b += 4) a += partial[b * 64 + j];  // coalesced
        red[tid] = a;
        __syncthreads();
        if (sl == 0) {
            float h = fc1_b[j] + red[j] + red[j + 64] + red[j + 128] + red[j + 192];
            h = fmaxf(h, 0.f);
#pragma unroll
            for (int k = 0; k < 2; k++) {
                float p = h * fc2_w[k * 64 + j];
#pragma unroll
                for (int o = 32; o > 0; o >>= 1) p += __shfl_down(p, o);
                if (j == 0) out[k] = p + fc2_b[k];
            }
        }
    }
}

// ---------------------------------------------------------------- launch
extern "C" void kernel_launch(void* const* d_in, const int* in_sizes, int n_in,
                              void* d_out, int out_size, void* d_ws, size_t ws_size,
                              hipStream_t stream) {
    const float* x     = (const float*)d_in[0];
    const float* ew    = (const float*)d_in[1];
    const float* W     = (const float*)d_in[2];
    const float* gamma = (const float*)d_in[3];
    const float* beta  = (const float*)d_in[4];
    const float* mean  = (const float*)d_in[5];
    const float* var   = (const float*)d_in[6];
    const float* fc1_w = (const float*)d_in[7];
    const float* fc1_b = (const float*)d_in[8];
    const float* fc2_w = (const float*)d_in[9];
    const float* fc2_b = (const float*)d_in[10];
    const int*   ei    = (const int*)d_in[11];
    float* out = (float*)d_out;

    // ws layout (4B elems):
    //   ctrl(16) | counts(NPAD) | off(NPAD) | cursor(NPAD) | bsum(256)
    //   | partial(GBLK*64=80000) | ep(int2 x E)            ~ 13.7 MB
    int*   ctrl    = (int*)d_ws;
    int*   counts  = ctrl + 16;
    int*   off     = counts + NPAD;
    int*   cursor  = off + NPAD;
    int*   bsum    = cursor + NPAD;
    float* partial = (float*)(bsum + 256);
    int2*  ep      = (int2*)(partial + GBLK * 64);   // offset is 8B-aligned
    (void)ws_size; (void)in_sizes; (void)n_in; (void)out_size;

    {   // zero ctrl + counts (everything else fully overwritten each call;
        // workspace is poisoned by the harness, so barriers/counters MUST be
        // explicitly zeroed every launch)
        int n4 = (16 + NPAD) / 4;                    // 12548
        zero_kernel<<<(n4 + 255) / 256, 256, 0, stream>>>((float4*)d_ws, n4);
    }
    csr_kernel<<<CSR_BLOCKS, CSR_THREADS, 0, stream>>>(ei, ew, ctrl, counts,
                                                       off, cursor, bsum, ep);
    gfc_kernel<<<GBLK, 256, 0, stream>>>(x, gamma, beta, mean, var, off, ep, W,
                                         fc1_w, fc1_b, fc2_w, fc2_b,
                                         partial, ctrl, out);
}

// Round 2
// 816.208 us; speedup vs baseline: 1.6704x; 1.6704x over previous
//
#include <hip/hip_runtime.h>

constexpr int N_NODES = 50000;
constexpr int E_EDGES = 1600000;
constexpr int NH      = N_NODES * 32;   // 1,600,000
constexpr float BN_EPS = 1e-5f;
constexpr int NPAD    = 50016;
constexpr int NBLK    = 625;            // fc1 chunk blocks

// ---------------------------------------------------------------- zero scratch
__global__ void zero_kernel(float4* __restrict__ p, int n4) {
    int i = blockIdx.x * blockDim.x + threadIdx.x;
    if (i < n4) p[i] = make_float4(0.f, 0.f, 0.f, 0.f);
}

// ---------------------------------------------------------------- CSR build
__global__ void hist_kernel(const int* __restrict__ ei, int* __restrict__ counts) {
    int e = blockIdx.x * blockDim.x + threadIdx.x;
    if (e < E_EDGES) atomicAdd(&counts[ei[E_EDGES + e]], 1);
}

__device__ inline int block_excl_scan(int v, int* s) {
    int t = threadIdx.x;
    s[t] = v;
    __syncthreads();
    for (int d = 1; d < 256; d <<= 1) {
        int x = (t >= d) ? s[t - d] : 0;
        __syncthreads();
        s[t] += x;
        __syncthreads();
    }
    return s[t] - v;   // exclusive
}

__global__ void scan1_kernel(const int* __restrict__ counts, int* __restrict__ bsum) {
    int i = blockIdx.x * 256 + threadIdx.x;
    int v = (i < N_NODES) ? counts[i] : 0;
#pragma unroll
    for (int o = 32; o > 0; o >>= 1) v += __shfl_down(v, o);
    __shared__ int s[4];
    int wave = threadIdx.x >> 6, lane = threadIdx.x & 63;
    if (lane == 0) s[wave] = v;
    __syncthreads();
    if (threadIdx.x == 0) bsum[blockIdx.x] = s[0] + s[1] + s[2] + s[3];
}

__global__ void scan2_kernel(int* __restrict__ bsum) {   // 1 block
    __shared__ int s[256];
    int t = threadIdx.x;
    int v = (t < 196) ? bsum[t] : 0;
    int excl = block_excl_scan(v, s);
    if (t < 196) bsum[t] = excl;
}

__global__ void scan3_kernel(const int* __restrict__ counts, const int* __restrict__ bsum,
                             int* __restrict__ off, int* __restrict__ cursor) {
    __shared__ int s[256];
    int i = blockIdx.x * 256 + threadIdx.x;
    int v = (i < N_NODES) ? counts[i] : 0;
    int excl = block_excl_scan(v, s) + bsum[blockIdx.x];
    if (i < N_NODES) { off[i] = excl; cursor[i] = excl; }
    if (i == N_NODES - 1) off[N_NODES] = excl + v;   // == E
}

// one interleaved int2 {tagged_src, w_bits} per edge: single 8B scattered store
__global__ void place_kernel(const int* __restrict__ ei, const float* __restrict__ ew,
                             int* __restrict__ cursor, int2* __restrict__ ep) {
    int e = blockIdx.x * blockDim.x + threadIdx.x;
    if (e < E_EDGES) {
        int src = ei[e];
        int dst = ei[E_EDGES + e];
        int pos = atomicAdd(&cursor[dst], 1);
        ep[pos] = make_int2(src | ((src == dst) ? 0x80000000 : 0),
                            __float_as_int(ew[e]));
    }
}

// ---------------------------------------------------------------- fused gather:
// BN + weighted neighbor sum + 32x32 W-contraction + relu.
// ONE WAVE PER NODE: 64 lanes = 2 edges x 32 channels.
//  - nb is wave-uniform -> zero intra-wave divergence (old version ran the
//    edge loop twice per wave because two 32-lane node groups diverged)
//  - edge records fetched by BROADCAST int2 loads (all 32 channel lanes read
//    the same address -> 1 transaction) instead of 2 ds_bpermutes per edge
//  - halves combined with one shfl_xor(32); contraction split cc 0..15/16..31
//    across halves (halves the cc loop), packed float2 LDS reads
__global__ void gather_kernel(const float* __restrict__ x,
                              const float* __restrict__ gamma,
                              const float* __restrict__ beta,
                              const float* __restrict__ mean,
                              const float* __restrict__ var,
                              const int*   __restrict__ off,
                              const int2*  __restrict__ ep,
                              const float* __restrict__ W,
                              float* __restrict__ rres) {
    __shared__ float2 s_wp[1024];            // {Wsum, W0} packed per (cc, h)
    __shared__ float  s_ap[4][64];           // per-wave {acc, acc0} interleaved
    int tid = threadIdx.x;
    for (int idx = tid; idx < 1024; idx += 256)
        s_wp[idx] = make_float2(W[1024 + idx] + W[2048 + idx], W[idx]);
    __syncthreads();

    int lane  = tid & 63;
    int c     = lane & 31;                   // channel
    int half  = lane >> 5;                   // which edge of the pair
    int wslot = tid >> 6;                    // wave slot in block
    int wid   = (blockIdx.x << 2) + wslot;   // global wave id, 0..24999

    float sc = gamma[c] * rsqrtf(var[c] + BN_EPS);
    float sh = beta[c] - mean[c] * sc;

    const float2* ap2 = (const float2*)s_ap[wslot];

#pragma unroll
    for (int i = 0; i < 2; i++) {            // 2 nodes per wave
        int n  = (wid << 1) + i;
        int e0 = off[n];
        int nb = off[n + 1] - e0;
        const int2* e2 = ep + e0;

        float acc = 0.f, acc0 = 0.f;
        int base = 0;
        for (; base + 8 <= nb; base += 8) {          // 4 pair-chunks in flight
#pragma unroll
            for (int k = 0; k < 4; k++) {
                int2 p = e2[base + (k << 1) + half]; // broadcast within half
                float vv = fmaf(x[(p.x & 0x7fffffff) * 32 + c], sc, sh);
                acc = fmaf(__int_as_float(p.y), vv, acc);
                if (p.x < 0) acc0 += vv;
            }
        }
        for (; base + 2 <= nb; base += 2) {          // pair tail
            int2 p = e2[base + half];
            float vv = fmaf(x[(p.x & 0x7fffffff) * 32 + c], sc, sh);
            acc = fmaf(__int_as_float(p.y), vv, acc);
            if (p.x < 0) acc0 += vv;
        }
        if (base < nb && half == 0) {                // odd edge: half 0 only
            int2 p = e2[base];
            float vv = fmaf(x[(p.x & 0x7fffffff) * 32 + c], sc, sh);
            acc = fmaf(__int_as_float(p.y), vv, acc);
            if (p.x < 0) acc0 += vv;
        }

        // combine halves -> both halves hold full acc/acc0 per channel c
        acc  += __shfl_xor(acc,  32);
        acc0 += __shfl_xor(acc0, 32);

        // stage {acc, acc0} interleaved; wave-private slot, no __syncthreads
        __builtin_amdgcn_wave_barrier();
        s_ap[wslot][(c << 1) | half] = half ? acc0 : acc;
        __threadfence_block();                       // drain ds_write (lgkmcnt)
        __builtin_amdgcn_wave_barrier();

        // contraction: half 0 sums cc=0..15, half 1 sums cc=16..31
        float r = 0.f;
        int ccb = half << 4;
#pragma unroll
        for (int t = 0; t < 16; t++) {
            int cc = ccb + t;
            float2 ap = ap2[cc];                     // broadcast per half
            float2 wp = s_wp[cc * 32 + c];
            r = fmaf(ap.x, wp.x, r);
            r = fmaf(ap.y, wp.y, r);
        }
        r += __shfl_xor(r, 32);
        if (half == 0) rres[n * 32 + c] = fmaxf(r, 0.f);
        __builtin_amdgcn_wave_barrier();
    }
}

// ---------------------------------------------------------------- fc1: [1,NH] @ [NH,64]^T
// 625 blocks, 4 waves, 16 rows/wave, LDS r-stage, atomic-free partials.
constexpr int CHUNK = 2560;   // 640 float4; NH/CHUNK = 625
__global__ void fc1_kernel(const float* __restrict__ r,
                           const float* __restrict__ w,
                           float* __restrict__ partial) {
    __shared__ float4 s_r[640];
    int tid = threadIdx.x;
    size_t ib = (size_t)blockIdx.x * CHUNK;
    const float4* r4 = (const float4*)(r + ib);
    for (int i = tid; i < 640; i += 256) s_r[i] = r4[i];
    __syncthreads();

    int wave = tid >> 6, lane = tid & 63;
    int jbase = wave * 16;
    float* pout = partial + blockIdx.x * 64;
    for (int jj = 0; jj < 16; jj += 2) {
        const float4* wa = (const float4*)(w + (size_t)(jbase + jj    ) * NH + ib);
        const float4* wb = (const float4*)(w + (size_t)(jbase + jj + 1) * NH + ib);
        float a0 = 0.f, a1 = 0.f;
#pragma unroll
        for (int k = 0; k < 10; k++) {
            float4 rv = s_r[lane + k * 64];
            float4 x0 = wa[lane + k * 64];
            float4 x1 = wb[lane + k * 64];
            a0 = fmaf(rv.x, x0.x, a0); a0 = fmaf(rv.y, x0.y, a0);
            a0 = fmaf(rv.z, x0.z, a0); a0 = fmaf(rv.w, x0.w, a0);
            a1 = fmaf(rv.x, x1.x, a1); a1 = fmaf(rv.y, x1.y, a1);
            a1 = fmaf(rv.z, x1.z, a1); a1 = fmaf(rv.w, x1.w, a1);
        }
#pragma unroll
        for (int o = 32; o > 0; o >>= 1) {
            a0 += __shfl_down(a0, o);
            a1 += __shfl_down(a1, o);
        }
        if (lane == 0) {
            pout[jbase + jj    ] = a0;   // plain store, distinct address per block
            pout[jbase + jj + 1] = a1;
        }
    }
}

// ---------------------------------------------------------------- reduce + head
__global__ void reduce_head_kernel(const float* __restrict__ partial,
                                   const float* __restrict__ fc1_b,
                                   const float* __restrict__ fc2_w,
                                   const float* __restrict__ fc2_b,
                                   float* __restrict__ out) {
    __shared__ float red[1024];
    int t = threadIdx.x;
    int j = t & 63, s = t >> 6;          // 16 slices over 625 blocks
    float a = 0.f;
    for (int b = s; b < NBLK; b += 16) a += partial[b * 64 + j];  // coalesced
    red[t] = a;
    __syncthreads();
    if (s == 0) {
        float h = fc1_b[j];
#pragma unroll
        for (int q = 0; q < 16; q++) h += red[q * 64 + j];
        h = fmaxf(h, 0.f);
#pragma unroll
        for (int k = 0; k < 2; k++) {
            float p = h * fc2_w[k * 64 + j];
#pragma unroll
            for (int o = 32; o > 0; o >>= 1) p += __shfl_down(p, o);
            if (j == 0) out[k] = p + fc2_b[k];
        }
    }
}

// ---------------------------------------------------------------- launch
extern "C" void kernel_launch(void* const* d_in, const int* in_sizes, int n_in,
                              void* d_out, int out_size, void* d_ws, size_t ws_size,
                              hipStream_t stream) {
    const float* x     = (const float*)d_in[0];
    const float* ew    = (const float*)d_in[1];
    const float* W     = (const float*)d_in[2];
    const float* gamma = (const float*)d_in[3];
    const float* beta  = (const float*)d_in[4];
    const float* mean  = (const float*)d_in[5];
    const float* var   = (const float*)d_in[6];
    const float* fc1_w = (const float*)d_in[7];
    const float* fc1_b = (const float*)d_in[8];
    const float* fc2_w = (const float*)d_in[9];
    const float* fc2_b = (const float*)d_in[10];
    const int*   ei    = (const int*)d_in[11];
    float* out = (float*)d_out;

    // ws layout (4B elems): partial(625*64=40000) | counts(NPAD) | off(NPAD)
    //   | cursor(NPAD) | bsum(256) | ep(int2 x E) | rres(NH)   ~ 20 MB
    float* partial = (float*)d_ws;
    int*   counts  = (int*)d_ws + 40000;
    int*   off     = (int*)d_ws + 40000 + NPAD;
    int*   cursor  = (int*)d_ws + 40000 + 2 * NPAD;
    int*   bsum    = (int*)d_ws + 40000 + 3 * NPAD;
    int2*  ep      = (int2*)(bsum + 256);       // 8B-aligned
    float* rres    = (float*)(ep + E_EDGES);
    (void)ws_size; (void)in_sizes; (void)n_in; (void)out_size;

    {   // zero counts only (partial fully overwritten by fc1 every call)
        int n4 = NPAD / 4;
        zero_kernel<<<(n4 + 255) / 256, 256, 0, stream>>>((float4*)counts, n4);
    }
    hist_kernel <<<(E_EDGES + 255) / 256, 256, 0, stream>>>(ei, counts);
    scan1_kernel<<<196, 256, 0, stream>>>(counts, bsum);
    scan2_kernel<<<1,   256, 0, stream>>>(bsum);
    scan3_kernel<<<196, 256, 0, stream>>>(counts, bsum, off, cursor);
    place_kernel<<<(E_EDGES + 255) / 256, 256, 0, stream>>>(ei, ew, cursor, ep);
    gather_kernel<<<N_NODES / 8, 256, 0, stream>>>(x, gamma, beta, mean, var,
                                                   off, ep, W, rres);
    fc1_kernel <<<NBLK, 256, 0, stream>>>(rres, fc1_w, partial);
    reduce_head_kernel<<<1, 1024, 0, stream>>>(partial, fc1_b, fc2_w, fc2_b, out);
}